// Round 6
// baseline (395.441 us; speedup 1.0000x reference)
//
#include <hip/hip_runtime.h>
#include <hip/hip_bf16.h>
#include <math.h>

// Problem constants
#define Bc 8
#define Nc 512
#define Tc 64
#define Cc 128
#define Mc 32
#define MEMc 20
#define Ec 4

// LDS strides (bf16 elements)
#define LDK  40   // sh_k  [64][40]
#define LDVT 72   // sh_vt [32][72]
#define LDP  72   // sh_p  [64][72] (post-barrier), aliased with sh_p2 [64][40] (pre-barrier)
#define LDP2 40

#define GRID_BLOCKS 2048
#define UNITS_PER_BLOCK 8   // bid-major: block bid owns units bid*8 .. bid*8+7 (same expert)

// Barrier WITHOUT vmcnt drain: LDS ordering only. Prefetched global->reg loads
// stay in flight across it (the compiler's __syncthreads would drain vmcnt(0)).
#define BAR() asm volatile("s_waitcnt lgkmcnt(0)\n\ts_barrier" ::: "memory")

typedef short bf16x8 __attribute__((ext_vector_type(8)));
typedef float f32x4  __attribute__((ext_vector_type(4)));

__device__ __forceinline__ unsigned short f2bfu(float f) {
    return __builtin_bit_cast(unsigned short, __float2bfloat16(f));
}
__device__ __forceinline__ unsigned pk2bf(float x, float y) {
    return ((unsigned)f2bfu(y) << 16) | (unsigned)f2bfu(x);
}

// ---- prep: wt[mat][e][m][c] bf16 (blocks 0..191); bankM[m][k] bf16 + G2[k][2] (block 192)
__global__ void prep(const float* __restrict__ Wq, const float* __restrict__ Wk,
                     const float* __restrict__ Wv, const float* __restrict__ membank,
                     const float* __restrict__ iq,
                     short* __restrict__ wt, short* __restrict__ bankM,
                     float* __restrict__ G2) {
    const int t = threadIdx.x;
    if (blockIdx.x < 192) {
        int idx = blockIdx.x * 256 + t;                 // 49152 = 3*4*32*128
        int c = idx & 127, m = (idx >> 7) & 31, e = (idx >> 12) & 3, mat = idx >> 14;
        const float* W = (mat == 0) ? Wq : (mat == 1) ? Wk : Wv;
        wt[idx] = (short)f2bfu(W[((size_t)e * Cc + c) * Mc + m]);
    } else {
        for (int idx = t; idx < Mc * 32; idx += 256) {
            int m = idx >> 5, k = idx & 31;
            bankM[idx] = (short)f2bfu((k < MEMc) ? membank[k * Mc + m] : 0.f);
        }
        if (t < MEMc) {
            float g0 = 0.f, g1 = 0.f;
            for (int m = 0; m < Mc; ++m) {
                float b = membank[t * Mc + m];
                g0 = fmaf(iq[m], b, g0);
                g1 = fmaf(iq[Mc + m], b, g1);
            }
            G2[2 * t]     = g0;
            G2[2 * t + 1] = g1;
        }
    }
}

__global__ __launch_bounds__(256, 5) void mg_mfma(
    const float* __restrict__ input,    // [B,N,T,2]
    const float* __restrict__ hidden,   // [E,B,N,T,C]
    const short* __restrict__ wt,       // [3][E][32][128] bf16
    const short* __restrict__ bankM,    // [32][32] bf16 (memory^T, K zero-padded)
    const float* __restrict__ G2,       // [20][2] fp32
    float* __restrict__ out)            // [B,N,T,1,E]
{
    __shared__ short sh_k [Tc * LDK];    // 5120 B
    __shared__ short sh_vt[Mc * LDVT];   // 4608 B
    __shared__ short sh_pu[Tc * LDP];    // 9216 B : P2 pre-barrier#2, P post-barrier#2
                                         // total 18944 B

    const int t    = threadIdx.x;
    const int w    = t >> 6;
    const int lane = t & 63;
    const int lo   = lane & 15;
    const int hi   = lane >> 4;
    const int bid  = blockIdx.x;

    const int unit0 = bid * UNITS_PER_BLOCK;
    const int e     = unit0 >> 12;                 // constant for the whole block
    const short* wb = wt + (((size_t)e * Mc) + lo) * Cc + hi * 8;   // block-constant

    // ---- preload unit 0 (registers; stays in flight until first use)
    float4 h4[8];
    float2 in2n;
    {
        const int bn0 = unit0 & 4095;
        in2n = *(const float2*)(input + ((size_t)bn0 * Tc + lane) * 2);
        const float* hrow = hidden + (((size_t)(e * 4096 + bn0)) * Tc + w * 16 + lo) * Cc + hi * 8;
        #pragma unroll
        for (int kt = 0; kt < 4; ++kt) {
            h4[2 * kt]     = *(const float4*)(hrow + kt * 32);
            h4[2 * kt + 1] = *(const float4*)(hrow + kt * 32 + 4);
        }
    }

    for (int it = 0; it < UNITS_PER_BLOCK; ++it) {
        const int bn_cur = (unit0 + it) & 4095;
        const int it_n   = (it < UNITS_PER_BLOCK - 1) ? it + 1 : it;   // clamp: harmless reload
        const int bn_nxt = (unit0 + it_n) & 4095;
        const float2 in2 = in2n;

        // ---- consume h4 -> bf16 A-frags (waits vmcnt here), then prefetch next unit
        bf16x8 a[4];
        #pragma unroll
        for (int kt = 0; kt < 4; ++kt) {
            const float4 x = h4[2 * kt], y = h4[2 * kt + 1];
            uint4 u = (uint4){pk2bf(x.x, x.y), pk2bf(x.z, x.w), pk2bf(y.x, y.y), pk2bf(y.z, y.w)};
            a[kt] = __builtin_bit_cast(bf16x8, u);
        }
        {
            in2n = *(const float2*)(input + ((size_t)bn_nxt * Tc + lane) * 2);
            const float* hrow = hidden + (((size_t)(e * 4096 + bn_nxt)) * Tc + w * 16 + lo) * Cc + hi * 8;
            #pragma unroll
            for (int kt = 0; kt < 4; ++kt) {
                h4[2 * kt]     = *(const float4*)(hrow + kt * 32);
                h4[2 * kt + 1] = *(const float4*)(hrow + kt * 32 + 4);
            }
        }

        BAR();   // #1: previous unit's LDS consumers (E/F reads) are done; vmcnt NOT drained

        // ---- B: mem-gate, row = lane, UNNORMALIZED exp (1/l cancels in cosine)
        {
            const bool mine = ((lane >> 4) == w);   // wave w owns rows [16w,16w+16), lane==row
            uint4* dst = (uint4*)&sh_pu[lane * LDP2];
            unsigned pd[4];
            #pragma unroll
            for (int kp = 0; kp < 4; ++kp) {
                const float4 g = *(const float4*)(G2 + 4 * kp);
                pd[kp] = pk2bf(__expf(in2.x * g.x + in2.y * g.y),
                               __expf(in2.x * g.z + in2.y * g.w));
            }
            if (mine) dst[0] = (uint4){pd[0], pd[1], pd[2], pd[3]};
            #pragma unroll
            for (int kp = 0; kp < 4; ++kp) {
                const float4 g = *(const float4*)(G2 + 16 + 4 * kp);
                pd[kp] = pk2bf(__expf(in2.x * g.x + in2.y * g.y),
                               __expf(in2.x * g.z + in2.y * g.w));
            }
            if (mine) dst[1] = (uint4){pd[0], pd[1], pd[2], pd[3]};
            {
                const float4 g = *(const float4*)(G2 + 32);
                pd[0] = pk2bf(__expf(in2.x * g.x + in2.y * g.y),
                              __expf(in2.x * g.z + in2.y * g.w));
                const float4 g2 = *(const float4*)(G2 + 36);
                pd[1] = pk2bf(__expf(in2.x * g2.x + in2.y * g2.y),
                              __expf(in2.x * g2.z + in2.y * g2.w));
            }
            if (mine) {
                dst[2] = (uint4){pd[0], pd[1], 0u, 0u};
                dst[3] = (uint4){0u, 0u, 0u, 0u};
            }
        }

        // ---- C: transposed projections  qT/kT/vT = W^T @ H^T
        f32x4 q_[2], k_[2], v_[2];
        #pragma unroll
        for (int nt = 0; nt < 2; ++nt) {
            q_[nt] = (f32x4){0.f, 0.f, 0.f, 0.f};
            k_[nt] = (f32x4){0.f, 0.f, 0.f, 0.f};
            v_[nt] = (f32x4){0.f, 0.f, 0.f, 0.f};
        }
        #pragma unroll
        for (int nt = 0; nt < 2; ++nt) {
            const short* p0 = wb + nt * 16 * Cc;
            #pragma unroll
            for (int kt = 0; kt < 4; ++kt) {
                const bf16x8 aq = *(const bf16x8*)(p0 + kt * 32);
                const bf16x8 ak = *(const bf16x8*)(p0 + 4 * Mc * Cc + kt * 32);
                const bf16x8 av = *(const bf16x8*)(p0 + 8 * Mc * Cc + kt * 32);
                q_[nt] = __builtin_amdgcn_mfma_f32_16x16x32_bf16(aq, a[kt], q_[nt], 0, 0, 0);
                k_[nt] = __builtin_amdgcn_mfma_f32_16x16x32_bf16(ak, a[kt], k_[nt], 0, 0, 0);
                v_[nt] = __builtin_amdgcn_mfma_f32_16x16x32_bf16(av, a[kt], v_[nt], 0, 0, 0);
            }
        }
        // K -> LDS row-major [s][m]; V -> LDS as V^T [m][s]
        unsigned q_pk[4];
        #pragma unroll
        for (int nt = 0; nt < 2; ++nt) {
            uint2 kw = (uint2){pk2bf(k_[nt][0], k_[nt][1]), pk2bf(k_[nt][2], k_[nt][3])};
            *(uint2*)&sh_k[(w * 16 + lo) * LDK + nt * 16 + hi * 4] = kw;
            #pragma unroll
            for (int j = 0; j < 4; ++j)
                sh_vt[(nt * 16 + hi * 4 + j) * LDVT + w * 16 + lo] = (short)f2bfu(v_[nt][j]);
            q_pk[nt * 2]     = pk2bf(q_[nt][0], q_[nt][1]);
            q_pk[nt * 2 + 1] = pk2bf(q_[nt][2], q_[nt][3]);
        }

        // ---- D: memories^T = bank^T @ P2^T (own wave's P2 rows; same-wave write->read)
        f32x4 am[2];
        am[0] = (f32x4){0.f, 0.f, 0.f, 0.f};
        am[1] = (f32x4){0.f, 0.f, 0.f, 0.f};
        {
            const bf16x8 bp2 = *(const bf16x8*)&sh_pu[(w * 16 + lo) * LDP2 + hi * 8];
            #pragma unroll
            for (int nt = 0; nt < 2; ++nt) {
                const bf16x8 ab = *(const bf16x8*)(bankM + (nt * 16 + lo) * 32 + hi * 8);
                am[nt] = __builtin_amdgcn_mfma_f32_16x16x32_bf16(ab, bp2, am[nt], 0, 0, 0);
            }
        }

        BAR();   // #2: sh_k/sh_vt complete, P2 consumed; vmcnt (next-unit prefetch) NOT drained

        // ---- E: energy^T = K @ Q^T. Q B-frag via ds_bpermute from q_pk.
        {
            const int A01 = (((hi & 1) * 32) + lo) << 2;
            const int A23 = A01 + 64;
            unsigned qb0, qb1, qb2, qb3;
            {
                unsigned l0 = __builtin_amdgcn_ds_bpermute(A01, (int)q_pk[0]);
                unsigned h0 = __builtin_amdgcn_ds_bpermute(A01, (int)q_pk[2]);
                unsigned l1 = __builtin_amdgcn_ds_bpermute(A01, (int)q_pk[1]);
                unsigned h1 = __builtin_amdgcn_ds_bpermute(A01, (int)q_pk[3]);
                unsigned l2 = __builtin_amdgcn_ds_bpermute(A23, (int)q_pk[0]);
                unsigned h2 = __builtin_amdgcn_ds_bpermute(A23, (int)q_pk[2]);
                unsigned l3 = __builtin_amdgcn_ds_bpermute(A23, (int)q_pk[1]);
                unsigned h3 = __builtin_amdgcn_ds_bpermute(A23, (int)q_pk[3]);
                qb0 = (hi < 2) ? l0 : h0;
                qb1 = (hi < 2) ? l1 : h1;
                qb2 = (hi < 2) ? l2 : h2;
                qb3 = (hi < 2) ? l3 : h3;
            }
            const bf16x8 bq = __builtin_bit_cast(bf16x8, (uint4){qb0, qb1, qb2, qb3});

            f32x4 en[4];
            #pragma unroll
            for (int st = 0; st < 4; ++st) {
                const bf16x8 akf = *(const bf16x8*)&sh_k[(st * 16 + lo) * LDK + hi * 8];
                en[st] = __builtin_amdgcn_mfma_f32_16x16x32_bf16(
                    akf, bq, (f32x4){0.f, 0.f, 0.f, 0.f}, 0, 0, 0);
            }
            float mx = -1e30f;
            #pragma unroll
            for (int st = 0; st < 4; ++st)
                #pragma unroll
                for (int j = 0; j < 4; ++j) mx = fmaxf(mx, en[st][j]);
            mx = fmaxf(mx, __shfl_xor(mx, 16));
            mx = fmaxf(mx, __shfl_xor(mx, 32));
            #pragma unroll
            for (int st = 0; st < 4; ++st) {
                uint2 pw = (uint2){pk2bf(__expf(en[st][0] - mx), __expf(en[st][1] - mx)),
                                   pk2bf(__expf(en[st][2] - mx), __expf(en[st][3] - mx))};
                *(uint2*)&sh_pu[(w * 16 + lo) * LDP + st * 16 + hi * 4] = pw;
            }
        }

        // ---- F: att^T = V^T @ P^T ; cosine vs in-register memories^T
        f32x4 av[2];
        av[0] = (f32x4){0.f, 0.f, 0.f, 0.f};
        av[1] = (f32x4){0.f, 0.f, 0.f, 0.f};
        {
            bf16x8 bp[2];
            #pragma unroll
            for (int kt = 0; kt < 2; ++kt)
                bp[kt] = *(const bf16x8*)&sh_pu[(w * 16 + lo) * LDP + kt * 32 + hi * 8];
            #pragma unroll
            for (int nt = 0; nt < 2; ++nt)
                #pragma unroll
                for (int kt = 0; kt < 2; ++kt) {
                    const bf16x8 avt = *(const bf16x8*)&sh_vt[(nt * 16 + lo) * LDVT + kt * 32 + hi * 8];
                    av[nt] = __builtin_amdgcn_mfma_f32_16x16x32_bf16(avt, bp[kt], av[nt], 0, 0, 0);
                }
        }
        {
            float d = 0.f, na = 0.f, nb = 0.f;
            #pragma unroll
            for (int nt = 0; nt < 2; ++nt)
                #pragma unroll
                for (int j = 0; j < 4; ++j) {
                    const float av_ = av[nt][j], am_ = am[nt][j];
                    d  = fmaf(av_, am_, d);
                    na = fmaf(av_, av_, na);
                    nb = fmaf(am_, am_, nb);
                }
            d  += __shfl_xor(d, 16);  d  += __shfl_xor(d, 32);
            na += __shfl_xor(na, 16); na += __shfl_xor(na, 32);
            nb += __shfl_xor(nb, 16); nb += __shfl_xor(nb, 32);
            if (hi == 0) {
                const float denom = fmaxf(sqrtf(na), 1e-8f) * fmaxf(sqrtf(nb), 1e-8f);
                out[((size_t)bn_cur * Tc + w * 16 + lo) * Ec + e] = d / denom;
            }
        }
    }
}

extern "C" void kernel_launch(void* const* d_in, const int* in_sizes, int n_in,
                              void* d_out, int out_size, void* d_ws, size_t ws_size,
                              hipStream_t stream) {
    const float* input   = (const float*)d_in[0];
    const float* hidden  = (const float*)d_in[1];
    const float* membank = (const float*)d_in[2];
    const float* iq      = (const float*)d_in[3];
    const float* Wq      = (const float*)d_in[4];
    const float* Wk      = (const float*)d_in[5];
    const float* Wv      = (const float*)d_in[6];
    float* out = (float*)d_out;

    short* wt    = (short*)d_ws;                       // 98304 B
    short* bankM = (short*)((char*)d_ws + 98304);      //  2048 B
    float* G2    = (float*)((char*)d_ws + 100352);     //   160 B

    prep<<<193, 256, 0, stream>>>(Wq, Wk, Wv, membank, iq, wt, bankM, G2);
    mg_mfma<<<GRID_BLOCKS, 256, 0, stream>>>(input, hidden, wt, bankM, G2, out);
}

// Round 7
// 249.226 us; speedup vs baseline: 1.5867x; 1.5867x over previous
//
#include <hip/hip_runtime.h>
#include <hip/hip_bf16.h>
#include <math.h>

// Problem constants
#define Bc 8
#define Nc 512
#define Tc 64
#define Cc 128
#define Mc 32
#define MEMc 20
#define Ec 4

// LDS strides (bf16 elements)
#define LDK  40   // sh_k  [64][40]
#define LDVT 72   // sh_vt [32][72]

typedef short bf16x8 __attribute__((ext_vector_type(8)));
typedef float f32x4  __attribute__((ext_vector_type(4)));

__device__ __forceinline__ unsigned short f2bfu(float f) {
    return __builtin_bit_cast(unsigned short, __float2bfloat16(f));
}
__device__ __forceinline__ unsigned pk2bf(float x, float y) {
    return ((unsigned)f2bfu(y) << 16) | (unsigned)f2bfu(x);
}

// ---- prep: wt[mat][e][m][c] bf16 (blocks 0..191); bankM[m][k] bf16 + G2[k][2] (block 192)
__global__ void prep(const float* __restrict__ Wq, const float* __restrict__ Wk,
                     const float* __restrict__ Wv, const float* __restrict__ membank,
                     const float* __restrict__ iq,
                     short* __restrict__ wt, short* __restrict__ bankM,
                     float* __restrict__ G2) {
    const int t = threadIdx.x;
    if (blockIdx.x < 192) {
        int idx = blockIdx.x * 256 + t;                 // 49152 = 3*4*32*128
        int c = idx & 127, m = (idx >> 7) & 31, e = (idx >> 12) & 3, mat = idx >> 14;
        const float* W = (mat == 0) ? Wq : (mat == 1) ? Wk : Wv;
        wt[idx] = (short)f2bfu(W[((size_t)e * Cc + c) * Mc + m]);
    } else {
        for (int idx = t; idx < Mc * 32; idx += 256) {
            int m = idx >> 5, k = idx & 31;
            bankM[idx] = (short)f2bfu((k < MEMc) ? membank[k * Mc + m] : 0.f);
        }
        if (t < MEMc) {
            float g0 = 0.f, g1 = 0.f;
            for (int m = 0; m < Mc; ++m) {
                float b = membank[t * Mc + m];
                g0 = fmaf(iq[m], b, g0);
                g1 = fmaf(iq[Mc + m], b, g1);
            }
            G2[2 * t]     = g0;
            G2[2 * t + 1] = g1;
        }
    }
}

__global__ __launch_bounds__(256, 5) void mg_mfma(
    const float* __restrict__ input,    // [B,N,T,2]
    const float* __restrict__ hidden,   // [E,B,N,T,C]
    const short* __restrict__ wt,       // [3][E][32][128] bf16
    const short* __restrict__ bankM,    // [32][32] bf16 (memory^T, K zero-padded)
    const float* __restrict__ G2,       // [20][2] fp32
    float* __restrict__ out)            // [B,N,T,1,E]
{
    __shared__ short sh_k [Tc * LDK];    // 5120 B
    __shared__ short sh_vt[Mc * LDVT];   // 4608 B  -> 9728 B total

    const int t    = threadIdx.x;
    const int w    = t >> 6;
    const int lane = t & 63;
    const int lo   = lane & 15;
    const int hi   = lane >> 4;
    const int bn   = blockIdx.x & 4095;
    const int e    = blockIdx.x >> 12;

    // ---- A: issue hidden + input loads first
    float4 h4[8];
    {
        const float* hrow = hidden + (((size_t)(e * 4096 + bn)) * Tc + w * 16 + lo) * Cc + hi * 8;
        #pragma unroll
        for (int kt = 0; kt < 4; ++kt) {
            h4[2 * kt]     = *(const float4*)(hrow + kt * 32);
            h4[2 * kt + 1] = *(const float4*)(hrow + kt * 32 + 4);
        }
    }
    const float2 in2 = *(const float2*)(input + ((size_t)bn * Tc + lane) * 2);

    // ---- B: mem-gate, row = lane, UNNORMALIZED exp (1/l cancels in cosine;
    //         logits input@G are O(0.1)). Every lane keeps its row's 20 exps in regs.
    unsigned pd[10];
    #pragma unroll
    for (int kp = 0; kp < 10; ++kp) {
        const float4 g = *(const float4*)(G2 + 4 * kp);   // slots 2kp, 2kp+1
        pd[kp] = pk2bf(__expf(in2.x * g.x + in2.y * g.y),
                       __expf(in2.x * g.z + in2.y * g.w));
    }

    // ---- C: transposed projections  qT/kT/vT = W^T @ H^T
    bf16x8 a[4];
    #pragma unroll
    for (int kt = 0; kt < 4; ++kt) {
        const float4 x = h4[2 * kt], y = h4[2 * kt + 1];
        uint4 u = (uint4){pk2bf(x.x, x.y), pk2bf(x.z, x.w), pk2bf(y.x, y.y), pk2bf(y.z, y.w)};
        a[kt] = __builtin_bit_cast(bf16x8, u);
    }
    f32x4 q_[2], k_[2], v_[2];
    #pragma unroll
    for (int nt = 0; nt < 2; ++nt) {
        q_[nt] = (f32x4){0.f, 0.f, 0.f, 0.f};
        k_[nt] = (f32x4){0.f, 0.f, 0.f, 0.f};
        v_[nt] = (f32x4){0.f, 0.f, 0.f, 0.f};
    }
    {
        const short* wb = wt + (((size_t)e * Mc) + lo) * Cc + hi * 8;
        #pragma unroll
        for (int nt = 0; nt < 2; ++nt) {
            const short* p0 = wb + nt * 16 * Cc;
            #pragma unroll
            for (int kt = 0; kt < 4; ++kt) {
                const bf16x8 aq = *(const bf16x8*)(p0 + kt * 32);
                const bf16x8 ak = *(const bf16x8*)(p0 + 4 * Mc * Cc + kt * 32);
                const bf16x8 av = *(const bf16x8*)(p0 + 8 * Mc * Cc + kt * 32);
                q_[nt] = __builtin_amdgcn_mfma_f32_16x16x32_bf16(aq, a[kt], q_[nt], 0, 0, 0);
                k_[nt] = __builtin_amdgcn_mfma_f32_16x16x32_bf16(ak, a[kt], k_[nt], 0, 0, 0);
                v_[nt] = __builtin_amdgcn_mfma_f32_16x16x32_bf16(av, a[kt], v_[nt], 0, 0, 0);
            }
        }
    }
    // K -> LDS row-major [s][m]; V -> LDS as V^T [m][s]; Q stays in regs (packed)
    unsigned q_pk[4];
    #pragma unroll
    for (int nt = 0; nt < 2; ++nt) {
        uint2 kw = (uint2){pk2bf(k_[nt][0], k_[nt][1]), pk2bf(k_[nt][2], k_[nt][3])};
        *(uint2*)&sh_k[(w * 16 + lo) * LDK + nt * 16 + hi * 4] = kw;
        #pragma unroll
        for (int j = 0; j < 4; ++j)
            sh_vt[(nt * 16 + hi * 4 + j) * LDVT + w * 16 + lo] = (short)f2bfu(v_[nt][j]);
        q_pk[nt * 2]     = pk2bf(q_[nt][0], q_[nt][1]);
        q_pk[nt * 2 + 1] = pk2bf(q_[nt][2], q_[nt][3]);
    }

    // ---- D: memories^T = bank^T @ P2^T.  P2 B-frag pulled from registers of
    //         lane w*16+lo via bpermute (no LDS, no barrier dependence).
    //         Need bp2[j] = P2[w*16+lo][hi*8+j]  -> pd word (hi*4+u), u=0..3; words >=10 are 0.
    f32x4 am[2];
    am[0] = (f32x4){0.f, 0.f, 0.f, 0.f};
    am[1] = (f32x4){0.f, 0.f, 0.f, 0.f};
    {
        const int addrD = (w * 16 + lo) * 4;
        unsigned Wd[10];
        #pragma unroll
        for (int u = 0; u < 10; ++u)
            Wd[u] = __builtin_amdgcn_ds_bpermute(addrD, (int)pd[u]);
        unsigned b2w[4];
        #pragma unroll
        for (int u = 0; u < 4; ++u) {
            const unsigned lo01 = (hi == 0) ? Wd[u] : Wd[4 + u];
            const unsigned hi23 = (u < 2) ? ((hi == 2) ? Wd[8 + u] : 0u) : 0u;
            b2w[u] = (hi < 2) ? lo01 : hi23;
        }
        const bf16x8 bp2 = __builtin_bit_cast(bf16x8, (uint4){b2w[0], b2w[1], b2w[2], b2w[3]});
        #pragma unroll
        for (int nt = 0; nt < 2; ++nt) {
            const bf16x8 ab = *(const bf16x8*)(bankM + (nt * 16 + lo) * 32 + hi * 8);
            am[nt] = __builtin_amdgcn_mfma_f32_16x16x32_bf16(ab, bp2, am[nt], 0, 0, 0);
        }
    }

    __syncthreads();   // the ONLY barrier: sh_k / sh_vt ready for cross-wave reads

    // ---- E: energy^T = K @ Q^T; Q B-frag via bpermute (r4-verified trick);
    //         NO max-subtraction (bounded logits; scale cancels in cosine).
    unsigned pw[4][2];
    {
        const int A01 = (((hi & 1) * 32) + lo) << 2;
        const int A23 = A01 + 64;
        unsigned qb0, qb1, qb2, qb3;
        {
            unsigned l0 = __builtin_amdgcn_ds_bpermute(A01, (int)q_pk[0]);
            unsigned h0 = __builtin_amdgcn_ds_bpermute(A01, (int)q_pk[2]);
            unsigned l1 = __builtin_amdgcn_ds_bpermute(A01, (int)q_pk[1]);
            unsigned h1 = __builtin_amdgcn_ds_bpermute(A01, (int)q_pk[3]);
            unsigned l2 = __builtin_amdgcn_ds_bpermute(A23, (int)q_pk[0]);
            unsigned h2 = __builtin_amdgcn_ds_bpermute(A23, (int)q_pk[2]);
            unsigned l3 = __builtin_amdgcn_ds_bpermute(A23, (int)q_pk[1]);
            unsigned h3 = __builtin_amdgcn_ds_bpermute(A23, (int)q_pk[3]);
            qb0 = (hi < 2) ? l0 : h0;
            qb1 = (hi < 2) ? l1 : h1;
            qb2 = (hi < 2) ? l2 : h2;
            qb3 = (hi < 2) ? l3 : h3;
        }
        const bf16x8 bq = __builtin_bit_cast(bf16x8, (uint4){qb0, qb1, qb2, qb3});

        #pragma unroll
        for (int st = 0; st < 4; ++st) {
            const bf16x8 akf = *(const bf16x8*)&sh_k[(st * 16 + lo) * LDK + hi * 8];
            const f32x4 en = __builtin_amdgcn_mfma_f32_16x16x32_bf16(
                akf, bq, (f32x4){0.f, 0.f, 0.f, 0.f}, 0, 0, 0);
            pw[st][0] = pk2bf(__expf(en[0]), __expf(en[1]));
            pw[st][1] = pk2bf(__expf(en[2]), __expf(en[3]));
        }
    }

    // ---- F: att^T = V^T @ P^T.  P B-frag from pw via bpermute:
    //         bp[kt] word u <-> cols kt*32+hi*8+{2u,2u+1} = pw[2kt+(hi>>1)][u&1]
    //         at src lane ((hi&1)*2+(u>>1))*16+lo.
    f32x4 av[2];
    av[0] = (f32x4){0.f, 0.f, 0.f, 0.f};
    av[1] = (f32x4){0.f, 0.f, 0.f, 0.f};
    {
        const int addrA = (((hi & 1) * 2 + 0) * 16 + lo) * 4;   // u = 0,1
        const int addrB = (((hi & 1) * 2 + 1) * 16 + lo) * 4;   // u = 2,3
        bf16x8 bp[2];
        #pragma unroll
        for (int kt = 0; kt < 2; ++kt) {
            unsigned wrd[4];
            #pragma unroll
            for (int u = 0; u < 4; ++u) {
                const int adr = (u < 2) ? addrA : addrB;
                const unsigned ev = __builtin_amdgcn_ds_bpermute(adr, (int)pw[2 * kt][u & 1]);
                const unsigned od = __builtin_amdgcn_ds_bpermute(adr, (int)pw[2 * kt + 1][u & 1]);
                wrd[u] = (hi < 2) ? ev : od;
            }
            bp[kt] = __builtin_bit_cast(bf16x8, (uint4){wrd[0], wrd[1], wrd[2], wrd[3]});
        }
        #pragma unroll
        for (int nt = 0; nt < 2; ++nt)
            #pragma unroll
            for (int kt = 0; kt < 2; ++kt) {
                const bf16x8 avt = *(const bf16x8*)&sh_vt[(nt * 16 + lo) * LDVT + kt * 32 + hi * 8];
                av[nt] = __builtin_amdgcn_mfma_f32_16x16x32_bf16(avt, bp[kt], av[nt], 0, 0, 0);
            }
    }

    // ---- cosine vs in-register memories^T, store
    {
        float d = 0.f, na = 0.f, nb = 0.f;
        #pragma unroll
        for (int nt = 0; nt < 2; ++nt)
            #pragma unroll
            for (int j = 0; j < 4; ++j) {
                const float av_ = av[nt][j], am_ = am[nt][j];
                d  = fmaf(av_, am_, d);
                na = fmaf(av_, av_, na);
                nb = fmaf(am_, am_, nb);
            }
        d  += __shfl_xor(d, 16);  d  += __shfl_xor(d, 32);
        na += __shfl_xor(na, 16); na += __shfl_xor(na, 32);
        nb += __shfl_xor(nb, 16); nb += __shfl_xor(nb, 32);
        if (hi == 0) {
            const float denom = fmaxf(sqrtf(na), 1e-8f) * fmaxf(sqrtf(nb), 1e-8f);
            out[((size_t)bn * Tc + w * 16 + lo) * Ec + e] = d / denom;
        }
    }
}

extern "C" void kernel_launch(void* const* d_in, const int* in_sizes, int n_in,
                              void* d_out, int out_size, void* d_ws, size_t ws_size,
                              hipStream_t stream) {
    const float* input   = (const float*)d_in[0];
    const float* hidden  = (const float*)d_in[1];
    const float* membank = (const float*)d_in[2];
    const float* iq      = (const float*)d_in[3];
    const float* Wq      = (const float*)d_in[4];
    const float* Wk      = (const float*)d_in[5];
    const float* Wv      = (const float*)d_in[6];
    float* out = (float*)d_out;

    short* wt    = (short*)d_ws;                       // 98304 B
    short* bankM = (short*)((char*)d_ws + 98304);      //  2048 B
    float* G2    = (float*)((char*)d_ws + 100352);     //   160 B

    prep<<<193, 256, 0, stream>>>(Wq, Wk, Wv, membank, iq, wt, bankM, G2);
    mg_mfma<<<Ec * Bc * Nc, 256, 0, stream>>>(input, hidden, wt, bankM, G2, out);
}

// Round 8
// 129.752 us; speedup vs baseline: 3.0477x; 1.9208x over previous
//
#include <hip/hip_runtime.h>
#include <hip/hip_bf16.h>
#include <math.h>

// Problem constants
#define Bc 8
#define Nc 512
#define Tc 64
#define Cc 128
#define Mc 32
#define MEMc 20
#define Ec 4

// LDS strides (bf16 elements)
#define LDK  40   // sh_k  [64][40]
#define LDVT 72   // sh_vt [32][72]

typedef short bf16x8 __attribute__((ext_vector_type(8)));
typedef float f32x4  __attribute__((ext_vector_type(4)));

__device__ __forceinline__ unsigned short f2bfu(float f) {
    return __builtin_bit_cast(unsigned short, __float2bfloat16(f));
}
__device__ __forceinline__ unsigned pk2bf(float x, float y) {
    return ((unsigned)f2bfu(y) << 16) | (unsigned)f2bfu(x);
}

// global->LDS direct DMA, 16 B per lane (dest = uniform base + lane*16)
__device__ __forceinline__ void gload_lds16(const void* g, void* l) {
    __builtin_amdgcn_global_load_lds(
        (const __attribute__((address_space(1))) unsigned int*)g,
        (__attribute__((address_space(3))) unsigned int*)l, 16, 0, 0);
}

// ---- prep (blocks 0..191): swizzled bf16 weight image wt_img[e][mat][m][c ^ ((m&7)<<3)]
//      so a LINEAR global_load_lds copy lands the T2-swizzled layout in LDS (m173 pattern).
//      block 192: bankM[m][k] bf16 (K zero-padded to 32) + G2[k][2] = iq @ membank^T.
__global__ void prep(const float* __restrict__ Wq, const float* __restrict__ Wk,
                     const float* __restrict__ Wv, const float* __restrict__ membank,
                     const float* __restrict__ iq,
                     short* __restrict__ wt_img, short* __restrict__ bankM,
                     float* __restrict__ G2) {
    const int t = threadIdx.x;
    if (blockIdx.x < 192) {
        int idx = blockIdx.x * 256 + t;                 // 49152 = 4*3*32*128
        int e   = idx / 12288;
        int r   = idx - e * 12288;
        int mat = r >> 12;
        int m   = (r >> 7) & 31;
        int c   = r & 127;
        const float* W = (mat == 0) ? Wq : (mat == 1) ? Wk : Wv;
        const int dst = e * 12288 + mat * 4096 + m * 128 + (c ^ ((m & 7) << 3));
        wt_img[dst] = (short)f2bfu(W[((size_t)e * Cc + c) * Mc + m]);
    } else {
        for (int idx = t; idx < Mc * 32; idx += 256) {
            int m = idx >> 5, k = idx & 31;
            bankM[idx] = (short)f2bfu((k < MEMc) ? membank[k * Mc + m] : 0.f);
        }
        if (t < MEMc) {
            float g0 = 0.f, g1 = 0.f;
            for (int m = 0; m < Mc; ++m) {
                float b = membank[t * Mc + m];
                g0 = fmaf(iq[m], b, g0);
                g1 = fmaf(iq[Mc + m], b, g1);
            }
            G2[2 * t]     = g0;
            G2[2 * t + 1] = g1;
        }
    }
}

__global__ __launch_bounds__(256, 4) void mg_mfma(
    const float* __restrict__ input,    // [B,N,T,2]
    const float* __restrict__ hidden,   // [E,B,N,T,C]
    const short* __restrict__ wt_img,   // [E][3][32][128] bf16, row-swizzled
    const short* __restrict__ bankM,    // [32][32] bf16 (memory^T, K zero-padded)
    const float* __restrict__ G2,       // [20][2] fp32
    float* __restrict__ out)            // [B,N,T,1,E]
{
    __shared__ __align__(16) short sh_wt[12288];   // 24576 B : this expert's q|k|v weights
    __shared__ __align__(16) short sh_k [Tc * LDK];    // 5120 B
    __shared__ __align__(16) short sh_vt[Mc * LDVT];   // 4608 B  -> 34304 B total

    const int t    = threadIdx.x;
    const int w    = t >> 6;
    const int lane = t & 63;
    const int lo   = lane & 15;
    const int hi   = lane >> 4;
    const int bn   = blockIdx.x & 4095;
    const int e    = blockIdx.x >> 12;

    // ---- A0: issue weight-slice DMA to LDS (6 x 4KB, linear; image pre-swizzled)
    {
        const short* gsrc = wt_img + (size_t)e * 12288 + w * 512 + lane * 8;
        short* ldst = sh_wt + w * 512;
        #pragma unroll
        for (int c = 0; c < 6; ++c)
            gload_lds16(gsrc + c * 2048, ldst + c * 2048);
    }

    // ---- A1: issue hidden + input register loads
    float4 h4[8];
    {
        const float* hrow = hidden + (((size_t)(e * 4096 + bn)) * Tc + w * 16 + lo) * Cc + hi * 8;
        #pragma unroll
        for (int kt = 0; kt < 4; ++kt) {
            h4[2 * kt]     = *(const float4*)(hrow + kt * 32);
            h4[2 * kt + 1] = *(const float4*)(hrow + kt * 32 + 4);
        }
    }
    const float2 in2 = *(const float2*)(input + ((size_t)bn * Tc + lane) * 2);

    // ---- B: mem-gate, row = lane, UNNORMALIZED exp (1/l cancels in cosine;
    //         logits input@G are O(0.1)). Lane keeps its row's 20 exps packed.
    unsigned pd[10];
    #pragma unroll
    for (int kp = 0; kp < 10; ++kp) {
        const float4 g = *(const float4*)(G2 + 4 * kp);   // slots 2kp, 2kp+1
        pd[kp] = pk2bf(__expf(in2.x * g.x + in2.y * g.y),
                       __expf(in2.x * g.z + in2.y * g.w));
    }

    // ---- convert A-frags (drains vmcnt: hidden regs AND the weight DMA)
    bf16x8 a[4];
    #pragma unroll
    for (int kt = 0; kt < 4; ++kt) {
        const float4 x = h4[2 * kt], y = h4[2 * kt + 1];
        uint4 u = (uint4){pk2bf(x.x, x.y), pk2bf(x.z, x.w), pk2bf(y.x, y.y), pk2bf(y.z, y.w)};
        a[kt] = __builtin_bit_cast(bf16x8, u);
    }

    __syncthreads();   // barrier #1: sh_wt visible to all waves

    // ---- C: transposed projections  qT/kT/vT = W^T @ H^T ; B-frags from LDS.
    //         read col = (kt*32 + hi*8) ^ swz, swz = (lo&7)<<3  (T2 swizzle -> 2-way max)
    f32x4 q_[2], k_[2], v_[2];
    #pragma unroll
    for (int nt = 0; nt < 2; ++nt) {
        q_[nt] = (f32x4){0.f, 0.f, 0.f, 0.f};
        k_[nt] = (f32x4){0.f, 0.f, 0.f, 0.f};
        v_[nt] = (f32x4){0.f, 0.f, 0.f, 0.f};
    }
    {
        const int swz = (lo & 7) << 3;
        int col[4];
        #pragma unroll
        for (int kt = 0; kt < 4; ++kt) col[kt] = (kt * 32 + hi * 8) ^ swz;
        const short* wrow = sh_wt + lo * 128;
        #pragma unroll
        for (int nt = 0; nt < 2; ++nt) {
            const short* p0 = wrow + nt * 2048;
            #pragma unroll
            for (int kt = 0; kt < 4; ++kt) {
                const bf16x8 aq = *(const bf16x8*)(p0 + col[kt]);
                const bf16x8 ak = *(const bf16x8*)(p0 + 4096 + col[kt]);
                const bf16x8 av = *(const bf16x8*)(p0 + 8192 + col[kt]);
                q_[nt] = __builtin_amdgcn_mfma_f32_16x16x32_bf16(aq, a[kt], q_[nt], 0, 0, 0);
                k_[nt] = __builtin_amdgcn_mfma_f32_16x16x32_bf16(ak, a[kt], k_[nt], 0, 0, 0);
                v_[nt] = __builtin_amdgcn_mfma_f32_16x16x32_bf16(av, a[kt], v_[nt], 0, 0, 0);
            }
        }
    }
    // K -> LDS row-major [s][m]; V -> LDS as V^T [m][s]; Q stays in regs (packed)
    unsigned q_pk[4];
    #pragma unroll
    for (int nt = 0; nt < 2; ++nt) {
        uint2 kw = (uint2){pk2bf(k_[nt][0], k_[nt][1]), pk2bf(k_[nt][2], k_[nt][3])};
        *(uint2*)&sh_k[(w * 16 + lo) * LDK + nt * 16 + hi * 4] = kw;
        #pragma unroll
        for (int j = 0; j < 4; ++j)
            sh_vt[(nt * 16 + hi * 4 + j) * LDVT + w * 16 + lo] = (short)f2bfu(v_[nt][j]);
        q_pk[nt * 2]     = pk2bf(q_[nt][0], q_[nt][1]);
        q_pk[nt * 2 + 1] = pk2bf(q_[nt][2], q_[nt][3]);
    }

    // ---- D: memories^T = bank^T @ P2^T.  P2 B-frag pulled from registers of
    //         lane w*16+lo via bpermute (no LDS, no barrier dependence).
    f32x4 am[2];
    am[0] = (f32x4){0.f, 0.f, 0.f, 0.f};
    am[1] = (f32x4){0.f, 0.f, 0.f, 0.f};
    {
        const int addrD = (w * 16 + lo) * 4;
        unsigned Wd[10];
        #pragma unroll
        for (int u = 0; u < 10; ++u)
            Wd[u] = __builtin_amdgcn_ds_bpermute(addrD, (int)pd[u]);
        unsigned b2w[4];
        #pragma unroll
        for (int u = 0; u < 4; ++u) {
            const unsigned lo01 = (hi == 0) ? Wd[u] : Wd[4 + u];
            const unsigned hi23 = (u < 2) ? ((hi == 2) ? Wd[8 + u] : 0u) : 0u;
            b2w[u] = (hi < 2) ? lo01 : hi23;
        }
        const bf16x8 bp2 = __builtin_bit_cast(bf16x8, (uint4){b2w[0], b2w[1], b2w[2], b2w[3]});
        #pragma unroll
        for (int nt = 0; nt < 2; ++nt) {
            const bf16x8 ab = *(const bf16x8*)(bankM + (nt * 16 + lo) * 32 + hi * 8);
            am[nt] = __builtin_amdgcn_mfma_f32_16x16x32_bf16(ab, bp2, am[nt], 0, 0, 0);
        }
    }

    __syncthreads();   // barrier #2: sh_k / sh_vt ready for cross-wave reads

    // ---- E: energy^T = K @ Q^T; Q B-frag via bpermute;
    //         NO max-subtraction (bounded logits; scale cancels in cosine).
    unsigned pw[4][2];
    {
        const int A01 = (((hi & 1) * 32) + lo) << 2;
        const int A23 = A01 + 64;
        unsigned qb0, qb1, qb2, qb3;
        {
            unsigned l0 = __builtin_amdgcn_ds_bpermute(A01, (int)q_pk[0]);
            unsigned h0 = __builtin_amdgcn_ds_bpermute(A01, (int)q_pk[2]);
            unsigned l1 = __builtin_amdgcn_ds_bpermute(A01, (int)q_pk[1]);
            unsigned h1 = __builtin_amdgcn_ds_bpermute(A01, (int)q_pk[3]);
            unsigned l2 = __builtin_amdgcn_ds_bpermute(A23, (int)q_pk[0]);
            unsigned h2 = __builtin_amdgcn_ds_bpermute(A23, (int)q_pk[2]);
            unsigned l3 = __builtin_amdgcn_ds_bpermute(A23, (int)q_pk[1]);
            unsigned h3 = __builtin_amdgcn_ds_bpermute(A23, (int)q_pk[3]);
            qb0 = (hi < 2) ? l0 : h0;
            qb1 = (hi < 2) ? l1 : h1;
            qb2 = (hi < 2) ? l2 : h2;
            qb3 = (hi < 2) ? l3 : h3;
        }
        const bf16x8 bq = __builtin_bit_cast(bf16x8, (uint4){qb0, qb1, qb2, qb3});

        #pragma unroll
        for (int st = 0; st < 4; ++st) {
            const bf16x8 akf = *(const bf16x8*)&sh_k[(st * 16 + lo) * LDK + hi * 8];
            const f32x4 en = __builtin_amdgcn_mfma_f32_16x16x32_bf16(
                akf, bq, (f32x4){0.f, 0.f, 0.f, 0.f}, 0, 0, 0);
            pw[st][0] = pk2bf(__expf(en[0]), __expf(en[1]));
            pw[st][1] = pk2bf(__expf(en[2]), __expf(en[3]));
        }
    }

    // ---- F: att^T = V^T @ P^T.  P B-frag from pw via bpermute.
    f32x4 av[2];
    av[0] = (f32x4){0.f, 0.f, 0.f, 0.f};
    av[1] = (f32x4){0.f, 0.f, 0.f, 0.f};
    {
        const int addrA = (((hi & 1) * 2 + 0) * 16 + lo) * 4;   // u = 0,1
        const int addrB = (((hi & 1) * 2 + 1) * 16 + lo) * 4;   // u = 2,3
        bf16x8 bp[2];
        #pragma unroll
        for (int kt = 0; kt < 2; ++kt) {
            unsigned wrd[4];
            #pragma unroll
            for (int u = 0; u < 4; ++u) {
                const int adr = (u < 2) ? addrA : addrB;
                const unsigned ev = __builtin_amdgcn_ds_bpermute(adr, (int)pw[2 * kt][u & 1]);
                const unsigned od = __builtin_amdgcn_ds_bpermute(adr, (int)pw[2 * kt + 1][u & 1]);
                wrd[u] = (hi < 2) ? ev : od;
            }
            bp[kt] = __builtin_bit_cast(bf16x8, (uint4){wrd[0], wrd[1], wrd[2], wrd[3]});
        }
        #pragma unroll
        for (int nt = 0; nt < 2; ++nt)
            #pragma unroll
            for (int kt = 0; kt < 2; ++kt) {
                const bf16x8 avt = *(const bf16x8*)&sh_vt[(nt * 16 + lo) * LDVT + kt * 32 + hi * 8];
                av[nt] = __builtin_amdgcn_mfma_f32_16x16x32_bf16(avt, bp[kt], av[nt], 0, 0, 0);
            }
    }

    // ---- cosine vs in-register memories^T, store
    {
        float d = 0.f, na = 0.f, nb = 0.f;
        #pragma unroll
        for (int nt = 0; nt < 2; ++nt)
            #pragma unroll
            for (int j = 0; j < 4; ++j) {
                const float av_ = av[nt][j], am_ = am[nt][j];
                d  = fmaf(av_, am_, d);
                na = fmaf(av_, av_, na);
                nb = fmaf(am_, am_, nb);
            }
        d  += __shfl_xor(d, 16);  d  += __shfl_xor(d, 32);
        na += __shfl_xor(na, 16); na += __shfl_xor(na, 32);
        nb += __shfl_xor(nb, 16); nb += __shfl_xor(nb, 32);
        if (hi == 0) {
            const float denom = fmaxf(sqrtf(na), 1e-8f) * fmaxf(sqrtf(nb), 1e-8f);
            out[((size_t)bn * Tc + w * 16 + lo) * Ec + e] = d / denom;
        }
    }
}

extern "C" void kernel_launch(void* const* d_in, const int* in_sizes, int n_in,
                              void* d_out, int out_size, void* d_ws, size_t ws_size,
                              hipStream_t stream) {
    const float* input   = (const float*)d_in[0];
    const float* hidden  = (const float*)d_in[1];
    const float* membank = (const float*)d_in[2];
    const float* iq      = (const float*)d_in[3];
    const float* Wq      = (const float*)d_in[4];
    const float* Wk      = (const float*)d_in[5];
    const float* Wv      = (const float*)d_in[6];
    float* out = (float*)d_out;

    short* wt_img = (short*)d_ws;                      // 98304 B
    short* bankM  = (short*)((char*)d_ws + 98304);     //  2048 B
    float* G2     = (float*)((char*)d_ws + 100352);    //   160 B

    prep<<<193, 256, 0, stream>>>(Wq, Wk, Wv, membank, iq, wt_img, bankM, G2);
    mg_mfma<<<Ec * Bc * Nc, 256, 0, stream>>>(input, hidden, wt_img, bankM, G2, out);
}

// Round 9
// 122.812 us; speedup vs baseline: 3.2199x; 1.0565x over previous
//
#include <hip/hip_runtime.h>
#include <hip/hip_bf16.h>
#include <math.h>

// Problem constants
#define Bc 8
#define Nc 512
#define Tc 64
#define Cc 128
#define Mc 32
#define MEMc 20
#define Ec 4

// LDS strides (bf16 elements)
#define LDK  40   // sh_k  [64][40]
#define LDVT 72   // sh_vt [32][72]

typedef short bf16x8 __attribute__((ext_vector_type(8)));
typedef float f32x4  __attribute__((ext_vector_type(4)));

__device__ __forceinline__ unsigned short f2bfu(float f) {
    return __builtin_bit_cast(unsigned short, __float2bfloat16(f));
}
__device__ __forceinline__ unsigned pk2bf(float x, float y) {
    return ((unsigned)f2bfu(y) << 16) | (unsigned)f2bfu(x);
}

// global->LDS direct DMA, 16 B per lane (dest = uniform base + lane*16)
__device__ __forceinline__ void gload_lds16(const void* g, void* l) {
    __builtin_amdgcn_global_load_lds(
        (const __attribute__((address_space(1))) unsigned int*)g,
        (__attribute__((address_space(3))) unsigned int*)l, 16, 0, 0);
}

// ---- prep (blocks 0..191): swizzled bf16 weight image wt_img[e][mat][m][c ^ ((m&7)<<3)]
//      block 192: bankM[m][k] bf16 (K zero-padded to 32) + G2[k][2] = iq @ membank^T.
__global__ void prep(const float* __restrict__ Wq, const float* __restrict__ Wk,
                     const float* __restrict__ Wv, const float* __restrict__ membank,
                     const float* __restrict__ iq,
                     short* __restrict__ wt_img, short* __restrict__ bankM,
                     float* __restrict__ G2) {
    const int t = threadIdx.x;
    if (blockIdx.x < 192) {
        int idx = blockIdx.x * 256 + t;                 // 49152 = 4*3*32*128
        int e   = idx / 12288;
        int r   = idx - e * 12288;
        int mat = r >> 12;
        int m   = (r >> 7) & 31;
        int c   = r & 127;
        const float* W = (mat == 0) ? Wq : (mat == 1) ? Wk : Wv;
        const int dst = e * 12288 + mat * 4096 + m * 128 + (c ^ ((m & 7) << 3));
        wt_img[dst] = (short)f2bfu(W[((size_t)e * Cc + c) * Mc + m]);
    } else {
        for (int idx = t; idx < Mc * 32; idx += 256) {
            int m = idx >> 5, k = idx & 31;
            bankM[idx] = (short)f2bfu((k < MEMc) ? membank[k * Mc + m] : 0.f);
        }
        if (t < MEMc) {
            float g0 = 0.f, g1 = 0.f;
            for (int m = 0; m < Mc; ++m) {
                float b = membank[t * Mc + m];
                g0 = fmaf(iq[m], b, g0);
                g1 = fmaf(iq[Mc + m], b, g1);
            }
            G2[2 * t]     = g0;
            G2[2 * t + 1] = g1;
        }
    }
}

__global__ __launch_bounds__(256, 3) void mg_mfma(
    const float* __restrict__ input,    // [B,N,T,2]
    const float* __restrict__ hidden,   // [E,B,N,T,C]
    const short* __restrict__ wt_img,   // [E][3][32][128] bf16, row-swizzled
    const short* __restrict__ bankM,    // [32][32] bf16 (memory^T, K zero-padded)
    const float* __restrict__ G2,       // [20][2] fp32
    float* __restrict__ out)            // [B,N,T,1,E]
{
    __shared__ __align__(16) short sh_wt[12288];          // 24576 B
    __shared__ __align__(16) short sh_k [2][Tc * LDK];    // 2 x 5120 B
    __shared__ __align__(16) short sh_vt[2][Mc * LDVT];   // 2 x 4608 B -> 44032 B total

    const int t    = threadIdx.x;
    const int w    = t >> 6;
    const int lane = t & 63;
    const int lo   = lane & 15;
    const int hi   = lane >> 4;
    const int e    = blockIdx.x >> 11;
    const int bn0  = (blockIdx.x & 2047) * 2;
    const int bn1  = bn0 + 1;

    // ---- A0: weight-slice DMA to LDS (6 x 4KB linear; image pre-swizzled)
    {
        const short* gsrc = wt_img + (size_t)e * 12288 + w * 512 + lane * 8;
        short* ldst = sh_wt + w * 512;
        #pragma unroll
        for (int c = 0; c < 6; ++c)
            gload_lds16(gsrc + c * 2048, ldst + c * 2048);
    }

    // ---- A1: issue BOTH units' input + hidden register loads (max MLP)
    const float2 in2_0 = *(const float2*)(input + ((size_t)bn0 * Tc + lane) * 2);
    const float2 in2_1 = *(const float2*)(input + ((size_t)bn1 * Tc + lane) * 2);
    float4 h0[8], h1[8];
    {
        const float* hr0 = hidden + (((size_t)(e * 4096 + bn0)) * Tc + w * 16 + lo) * Cc + hi * 8;
        const float* hr1 = hidden + (((size_t)(e * 4096 + bn1)) * Tc + w * 16 + lo) * Cc + hi * 8;
        #pragma unroll
        for (int kt = 0; kt < 4; ++kt) {
            h0[2 * kt]     = *(const float4*)(hr0 + kt * 32);
            h0[2 * kt + 1] = *(const float4*)(hr0 + kt * 32 + 4);
            h1[2 * kt]     = *(const float4*)(hr1 + kt * 32);
            h1[2 * kt + 1] = *(const float4*)(hr1 + kt * 32 + 4);
        }
    }

    // ---- B: mem-gate per unit, row = lane, UNNORMALIZED exp (1/l cancels in cosine)
    unsigned pd0[10], pd1[10];
    #pragma unroll
    for (int kp = 0; kp < 10; ++kp) {
        const float4 g = *(const float4*)(G2 + 4 * kp);
        pd0[kp] = pk2bf(__expf(in2_0.x * g.x + in2_0.y * g.y),
                        __expf(in2_0.x * g.z + in2_0.y * g.w));
        pd1[kp] = pk2bf(__expf(in2_1.x * g.x + in2_1.y * g.y),
                        __expf(in2_1.x * g.z + in2_1.y * g.w));
    }

    // ---- D (hoisted): memories^T = bank^T @ P2^T per unit; reg-only bpermute,
    //      independent of weights/hidden -> fills the load shadow; frees pd.
    f32x4 am0[2], am1[2];
    am0[0] = am0[1] = (f32x4){0.f, 0.f, 0.f, 0.f};
    am1[0] = am1[1] = (f32x4){0.f, 0.f, 0.f, 0.f};
    {
        const int addrD = (w * 16 + lo) * 4;
        unsigned W0[10], W1[10];
        #pragma unroll
        for (int u = 0; u < 10; ++u) {
            W0[u] = __builtin_amdgcn_ds_bpermute(addrD, (int)pd0[u]);
            W1[u] = __builtin_amdgcn_ds_bpermute(addrD, (int)pd1[u]);
        }
        unsigned b0[4], b1[4];
        #pragma unroll
        for (int u = 0; u < 4; ++u) {
            const unsigned l0 = (hi == 0) ? W0[u] : W0[4 + u];
            const unsigned h0_ = (u < 2) ? ((hi == 2) ? W0[8 + u] : 0u) : 0u;
            b0[u] = (hi < 2) ? l0 : h0_;
            const unsigned l1 = (hi == 0) ? W1[u] : W1[4 + u];
            const unsigned h1_ = (u < 2) ? ((hi == 2) ? W1[8 + u] : 0u) : 0u;
            b1[u] = (hi < 2) ? l1 : h1_;
        }
        const bf16x8 bp20 = __builtin_bit_cast(bf16x8, (uint4){b0[0], b0[1], b0[2], b0[3]});
        const bf16x8 bp21 = __builtin_bit_cast(bf16x8, (uint4){b1[0], b1[1], b1[2], b1[3]});
        #pragma unroll
        for (int nt = 0; nt < 2; ++nt) {
            const bf16x8 ab = *(const bf16x8*)(bankM + (nt * 16 + lo) * 32 + hi * 8);
            am0[nt] = __builtin_amdgcn_mfma_f32_16x16x32_bf16(ab, bp20, am0[nt], 0, 0, 0);
            am1[nt] = __builtin_amdgcn_mfma_f32_16x16x32_bf16(ab, bp21, am1[nt], 0, 0, 0);
        }
    }

    // ---- convert A-frags for both units (drains hidden loads; frees h regs)
    bf16x8 a0[4], a1[4];
    #pragma unroll
    for (int kt = 0; kt < 4; ++kt) {
        const float4 x0 = h0[2 * kt], y0 = h0[2 * kt + 1];
        a0[kt] = __builtin_bit_cast(bf16x8, (uint4){pk2bf(x0.x, x0.y), pk2bf(x0.z, x0.w),
                                                    pk2bf(y0.x, y0.y), pk2bf(y0.z, y0.w)});
        const float4 x1 = h1[2 * kt], y1 = h1[2 * kt + 1];
        a1[kt] = __builtin_bit_cast(bf16x8, (uint4){pk2bf(x1.x, x1.y), pk2bf(x1.z, x1.w),
                                                    pk2bf(y1.x, y1.y), pk2bf(y1.z, y1.w)});
    }

    __syncthreads();   // barrier #1: sh_wt visible

    // ---- C: projections for BOTH units; each weight frag feeds 6 MFMAs
    f32x4 q0_[2], k0_[2], v0_[2], q1_[2], k1_[2], v1_[2];
    #pragma unroll
    for (int nt = 0; nt < 2; ++nt) {
        q0_[nt] = k0_[nt] = v0_[nt] = (f32x4){0.f, 0.f, 0.f, 0.f};
        q1_[nt] = k1_[nt] = v1_[nt] = (f32x4){0.f, 0.f, 0.f, 0.f};
    }
    {
        const int swz = (lo & 7) << 3;
        int col[4];
        #pragma unroll
        for (int kt = 0; kt < 4; ++kt) col[kt] = (kt * 32 + hi * 8) ^ swz;
        const short* wrow = sh_wt + lo * 128;
        #pragma unroll
        for (int nt = 0; nt < 2; ++nt) {
            const short* p0 = wrow + nt * 2048;
            #pragma unroll
            for (int kt = 0; kt < 4; ++kt) {
                const bf16x8 wq = *(const bf16x8*)(p0 + col[kt]);
                const bf16x8 wk = *(const bf16x8*)(p0 + 4096 + col[kt]);
                const bf16x8 wv = *(const bf16x8*)(p0 + 8192 + col[kt]);
                q0_[nt] = __builtin_amdgcn_mfma_f32_16x16x32_bf16(wq, a0[kt], q0_[nt], 0, 0, 0);
                k0_[nt] = __builtin_amdgcn_mfma_f32_16x16x32_bf16(wk, a0[kt], k0_[nt], 0, 0, 0);
                v0_[nt] = __builtin_amdgcn_mfma_f32_16x16x32_bf16(wv, a0[kt], v0_[nt], 0, 0, 0);
                q1_[nt] = __builtin_amdgcn_mfma_f32_16x16x32_bf16(wq, a1[kt], q1_[nt], 0, 0, 0);
                k1_[nt] = __builtin_amdgcn_mfma_f32_16x16x32_bf16(wk, a1[kt], k1_[nt], 0, 0, 0);
                v1_[nt] = __builtin_amdgcn_mfma_f32_16x16x32_bf16(wv, a1[kt], v1_[nt], 0, 0, 0);
            }
        }
    }
    // K -> LDS row-major [s][m]; V -> LDS as V^T [m][s]; Q packed in regs
    unsigned q_pk0[4], q_pk1[4];
    #pragma unroll
    for (int nt = 0; nt < 2; ++nt) {
        *(uint2*)&sh_k[0][(w * 16 + lo) * LDK + nt * 16 + hi * 4] =
            (uint2){pk2bf(k0_[nt][0], k0_[nt][1]), pk2bf(k0_[nt][2], k0_[nt][3])};
        *(uint2*)&sh_k[1][(w * 16 + lo) * LDK + nt * 16 + hi * 4] =
            (uint2){pk2bf(k1_[nt][0], k1_[nt][1]), pk2bf(k1_[nt][2], k1_[nt][3])};
        #pragma unroll
        for (int j = 0; j < 4; ++j) {
            sh_vt[0][(nt * 16 + hi * 4 + j) * LDVT + w * 16 + lo] = (short)f2bfu(v0_[nt][j]);
            sh_vt[1][(nt * 16 + hi * 4 + j) * LDVT + w * 16 + lo] = (short)f2bfu(v1_[nt][j]);
        }
        q_pk0[nt * 2]     = pk2bf(q0_[nt][0], q0_[nt][1]);
        q_pk0[nt * 2 + 1] = pk2bf(q0_[nt][2], q0_[nt][3]);
        q_pk1[nt * 2]     = pk2bf(q1_[nt][0], q1_[nt][1]);
        q_pk1[nt * 2 + 1] = pk2bf(q1_[nt][2], q1_[nt][3]);
    }

    __syncthreads();   // barrier #2: sh_k / sh_vt ready

    // ---- E+F per unit (two independent chains; compiler interleaves)
    const int A01   = (((hi & 1) * 32) + lo) << 2;
    const int A23   = A01 + 64;
    const int addrA = (((hi & 1) * 2 + 0) * 16 + lo) * 4;
    const int addrB = (((hi & 1) * 2 + 1) * 16 + lo) * 4;

    #pragma unroll
    for (int u = 0; u < 2; ++u) {
        const unsigned* q_pk = u ? q_pk1 : q_pk0;
        const f32x4*    am   = u ? am1   : am0;
        const int       bn   = u ? bn1   : bn0;

        // E: energy^T = K @ Q^T; Q B-frag via bpermute; no max-subtraction
        unsigned pw[4][2];
        {
            unsigned l0 = __builtin_amdgcn_ds_bpermute(A01, (int)q_pk[0]);
            unsigned h0_ = __builtin_amdgcn_ds_bpermute(A01, (int)q_pk[2]);
            unsigned l1 = __builtin_amdgcn_ds_bpermute(A01, (int)q_pk[1]);
            unsigned h1_ = __builtin_amdgcn_ds_bpermute(A01, (int)q_pk[3]);
            unsigned l2 = __builtin_amdgcn_ds_bpermute(A23, (int)q_pk[0]);
            unsigned h2_ = __builtin_amdgcn_ds_bpermute(A23, (int)q_pk[2]);
            unsigned l3 = __builtin_amdgcn_ds_bpermute(A23, (int)q_pk[1]);
            unsigned h3_ = __builtin_amdgcn_ds_bpermute(A23, (int)q_pk[3]);
            const bf16x8 bq = __builtin_bit_cast(bf16x8, (uint4){
                (hi < 2) ? l0 : h0_, (hi < 2) ? l1 : h1_,
                (hi < 2) ? l2 : h2_, (hi < 2) ? l3 : h3_});
            #pragma unroll
            for (int st = 0; st < 4; ++st) {
                const bf16x8 akf = *(const bf16x8*)&sh_k[u][(st * 16 + lo) * LDK + hi * 8];
                const f32x4 en = __builtin_amdgcn_mfma_f32_16x16x32_bf16(
                    akf, bq, (f32x4){0.f, 0.f, 0.f, 0.f}, 0, 0, 0);
                pw[st][0] = pk2bf(__expf(en[0]), __expf(en[1]));
                pw[st][1] = pk2bf(__expf(en[2]), __expf(en[3]));
            }
        }

        // F: att^T = V^T @ P^T; P B-frag from pw via bpermute
        f32x4 av[2];
        av[0] = av[1] = (f32x4){0.f, 0.f, 0.f, 0.f};
        {
            bf16x8 bp[2];
            #pragma unroll
            for (int kt = 0; kt < 2; ++kt) {
                unsigned wrd[4];
                #pragma unroll
                for (int uu = 0; uu < 4; ++uu) {
                    const int adr = (uu < 2) ? addrA : addrB;
                    const unsigned ev = __builtin_amdgcn_ds_bpermute(adr, (int)pw[2 * kt][uu & 1]);
                    const unsigned od = __builtin_amdgcn_ds_bpermute(adr, (int)pw[2 * kt + 1][uu & 1]);
                    wrd[uu] = (hi < 2) ? ev : od;
                }
                bp[kt] = __builtin_bit_cast(bf16x8, (uint4){wrd[0], wrd[1], wrd[2], wrd[3]});
            }
            #pragma unroll
            for (int nt = 0; nt < 2; ++nt)
                #pragma unroll
                for (int kt = 0; kt < 2; ++kt) {
                    const bf16x8 avt = *(const bf16x8*)&sh_vt[u][(nt * 16 + lo) * LDVT + kt * 32 + hi * 8];
                    av[nt] = __builtin_amdgcn_mfma_f32_16x16x32_bf16(avt, bp[kt], av[nt], 0, 0, 0);
                }
        }

        // cosine vs in-register memories^T, store
        float d = 0.f, na = 0.f, nb = 0.f;
        #pragma unroll
        for (int nt = 0; nt < 2; ++nt)
            #pragma unroll
            for (int j = 0; j < 4; ++j) {
                const float av_ = av[nt][j], am_ = am[nt][j];
                d  = fmaf(av_, am_, d);
                na = fmaf(av_, av_, na);
                nb = fmaf(am_, am_, nb);
            }
        d  += __shfl_xor(d, 16);  d  += __shfl_xor(d, 32);
        na += __shfl_xor(na, 16); na += __shfl_xor(na, 32);
        nb += __shfl_xor(nb, 16); nb += __shfl_xor(nb, 32);
        if (hi == 0) {
            const float denom = fmaxf(sqrtf(na), 1e-8f) * fmaxf(sqrtf(nb), 1e-8f);
            out[((size_t)bn * Tc + w * 16 + lo) * Ec + e] = d / denom;
        }
    }
}

extern "C" void kernel_launch(void* const* d_in, const int* in_sizes, int n_in,
                              void* d_out, int out_size, void* d_ws, size_t ws_size,
                              hipStream_t stream) {
    const float* input   = (const float*)d_in[0];
    const float* hidden  = (const float*)d_in[1];
    const float* membank = (const float*)d_in[2];
    const float* iq      = (const float*)d_in[3];
    const float* Wq      = (const float*)d_in[4];
    const float* Wk      = (const float*)d_in[5];
    const float* Wv      = (const float*)d_in[6];
    float* out = (float*)d_out;

    short* wt_img = (short*)d_ws;                      // 98304 B
    short* bankM  = (short*)((char*)d_ws + 98304);     //  2048 B
    float* G2     = (float*)((char*)d_ws + 100352);    //   160 B

    prep<<<193, 256, 0, stream>>>(Wq, Wk, Wv, membank, iq, wt_img, bankM, G2);
    mg_mfma<<<Ec * Bc * Nc / 2, 256, 0, stream>>>(input, hidden, wt_img, bankM, G2, out);
}

// Round 10
// 121.504 us; speedup vs baseline: 3.2546x; 1.0108x over previous
//
#include <hip/hip_runtime.h>
#include <hip/hip_bf16.h>
#include <math.h>

// Problem constants
#define Bc 8
#define Nc 512
#define Tc 64
#define Cc 128
#define Mc 32
#define MEMc 20
#define Ec 4

// LDS strides (bf16 elements)
#define LDK  40   // sh_k  [64][40]
#define LDVT 72   // sh_vt [32][72]

typedef short bf16x8 __attribute__((ext_vector_type(8)));
typedef float f32x4  __attribute__((ext_vector_type(4)));

__device__ __forceinline__ unsigned short f2bfu(float f) {
    return __builtin_bit_cast(unsigned short, __float2bfloat16(f));
}
__device__ __forceinline__ unsigned pk2bf(float x, float y) {
    return ((unsigned)f2bfu(y) << 16) | (unsigned)f2bfu(x);
}

// global->LDS direct DMA, 16 B per lane (dest = uniform base + lane*16)
__device__ __forceinline__ void gload_lds16(const void* g, void* l) {
    __builtin_amdgcn_global_load_lds(
        (const __attribute__((address_space(1))) unsigned int*)g,
        (__attribute__((address_space(3))) unsigned int*)l, 16, 0, 0);
}

// ---- prep (blocks 0..191): swizzled bf16 weight image wt_img[e][mat][m][c ^ ((m&7)<<3)]
//      block 192: bankM[m][k] bf16 (K zero-padded to 32) + G2[k][2] = iq @ membank^T.
__global__ void prep(const float* __restrict__ Wq, const float* __restrict__ Wk,
                     const float* __restrict__ Wv, const float* __restrict__ membank,
                     const float* __restrict__ iq,
                     short* __restrict__ wt_img, short* __restrict__ bankM,
                     float* __restrict__ G2) {
    const int t = threadIdx.x;
    if (blockIdx.x < 192) {
        int idx = blockIdx.x * 256 + t;                 // 49152 = 4*3*32*128
        int e   = idx / 12288;
        int r   = idx - e * 12288;
        int mat = r >> 12;
        int m   = (r >> 7) & 31;
        int c   = r & 127;
        const float* W = (mat == 0) ? Wq : (mat == 1) ? Wk : Wv;
        const int dst = e * 12288 + mat * 4096 + m * 128 + (c ^ ((m & 7) << 3));
        wt_img[dst] = (short)f2bfu(W[((size_t)e * Cc + c) * Mc + m]);
    } else {
        for (int idx = t; idx < Mc * 32; idx += 256) {
            int m = idx >> 5, k = idx & 31;
            bankM[idx] = (short)f2bfu((k < MEMc) ? membank[k * Mc + m] : 0.f);
        }
        if (t < MEMc) {
            float g0 = 0.f, g1 = 0.f;
            for (int m = 0; m < Mc; ++m) {
                float b = membank[t * Mc + m];
                g0 = fmaf(iq[m], b, g0);
                g1 = fmaf(iq[Mc + m], b, g1);
            }
            G2[2 * t]     = g0;
            G2[2 * t + 1] = g1;
        }
    }
}

// ---- projection for one unit: q/k/v^T = W^T @ H^T (B-frags from swizzled sh_wt)
__device__ __forceinline__ void proj(const short* __restrict__ sh_wt, const bf16x8* a,
                                     int lo, int hi,
                                     f32x4 q_[2], f32x4 k_[2], f32x4 v_[2]) {
    #pragma unroll
    for (int nt = 0; nt < 2; ++nt)
        q_[nt] = k_[nt] = v_[nt] = (f32x4){0.f, 0.f, 0.f, 0.f};
    const int swz = (lo & 7) << 3;
    int col[4];
    #pragma unroll
    for (int kt = 0; kt < 4; ++kt) col[kt] = (kt * 32 + hi * 8) ^ swz;
    const short* wrow = sh_wt + lo * 128;
    #pragma unroll
    for (int nt = 0; nt < 2; ++nt) {
        const short* p0 = wrow + nt * 2048;
        #pragma unroll
        for (int kt = 0; kt < 4; ++kt) {
            const bf16x8 wq = *(const bf16x8*)(p0 + col[kt]);
            const bf16x8 wk = *(const bf16x8*)(p0 + 4096 + col[kt]);
            const bf16x8 wv = *(const bf16x8*)(p0 + 8192 + col[kt]);
            q_[nt] = __builtin_amdgcn_mfma_f32_16x16x32_bf16(wq, a[kt], q_[nt], 0, 0, 0);
            k_[nt] = __builtin_amdgcn_mfma_f32_16x16x32_bf16(wk, a[kt], k_[nt], 0, 0, 0);
            v_[nt] = __builtin_amdgcn_mfma_f32_16x16x32_bf16(wv, a[kt], v_[nt], 0, 0, 0);
        }
    }
}

// ---- mem-gate exps (packed bf16 pairs), unnormalized
__device__ __forceinline__ void gate_pd(const float* __restrict__ G2, float2 in2, unsigned pd[10]) {
    #pragma unroll
    for (int kp = 0; kp < 10; ++kp) {
        const float4 g = *(const float4*)(G2 + 4 * kp);
        pd[kp] = pk2bf(__expf(in2.x * g.x + in2.y * g.y),
                       __expf(in2.x * g.z + in2.y * g.w));
    }
}

// ---- memories^T = bank^T @ P2^T (reg-only bpermute B-frag)
__device__ __forceinline__ void mem_read(const short* __restrict__ bankM,
                                         const unsigned pd[10], int lo, int hi, int w,
                                         f32x4 am[2]) {
    am[0] = am[1] = (f32x4){0.f, 0.f, 0.f, 0.f};
    const int addrD = (w * 16 + lo) * 4;
    unsigned Wd[10];
    #pragma unroll
    for (int u = 0; u < 10; ++u)
        Wd[u] = __builtin_amdgcn_ds_bpermute(addrD, (int)pd[u]);
    unsigned b[4];
    #pragma unroll
    for (int u = 0; u < 4; ++u) {
        const unsigned l_ = (hi == 0) ? Wd[u] : Wd[4 + u];
        const unsigned h_ = (u < 2) ? ((hi == 2) ? Wd[8 + u] : 0u) : 0u;
        b[u] = (hi < 2) ? l_ : h_;
    }
    const bf16x8 bp2 = __builtin_bit_cast(bf16x8, (uint4){b[0], b[1], b[2], b[3]});
    #pragma unroll
    for (int nt = 0; nt < 2; ++nt) {
        const bf16x8 ab = *(const bf16x8*)(bankM + (nt * 16 + lo) * 32 + hi * 8);
        am[nt] = __builtin_amdgcn_mfma_f32_16x16x32_bf16(ab, bp2, am[nt], 0, 0, 0);
    }
}

// ---- E + F + cosine + store for one unit
__device__ __forceinline__ void attend_store(
    const short* __restrict__ shk, const short* __restrict__ shv,
    const unsigned q_pk[4], const f32x4 am[2],
    int lo, int hi, int w, int A01, int A23, int addrA, int addrB,
    int bn, int e, float* __restrict__ out) {
    // E: energy^T = K @ Q^T; Q B-frag via bpermute; no max-subtraction
    unsigned pw[4][2];
    {
        unsigned l0 = __builtin_amdgcn_ds_bpermute(A01, (int)q_pk[0]);
        unsigned h0_ = __builtin_amdgcn_ds_bpermute(A01, (int)q_pk[2]);
        unsigned l1 = __builtin_amdgcn_ds_bpermute(A01, (int)q_pk[1]);
        unsigned h1_ = __builtin_amdgcn_ds_bpermute(A01, (int)q_pk[3]);
        unsigned l2 = __builtin_amdgcn_ds_bpermute(A23, (int)q_pk[0]);
        unsigned h2_ = __builtin_amdgcn_ds_bpermute(A23, (int)q_pk[2]);
        unsigned l3 = __builtin_amdgcn_ds_bpermute(A23, (int)q_pk[1]);
        unsigned h3_ = __builtin_amdgcn_ds_bpermute(A23, (int)q_pk[3]);
        const bf16x8 bq = __builtin_bit_cast(bf16x8, (uint4){
            (hi < 2) ? l0 : h0_, (hi < 2) ? l1 : h1_,
            (hi < 2) ? l2 : h2_, (hi < 2) ? l3 : h3_});
        #pragma unroll
        for (int st = 0; st < 4; ++st) {
            const bf16x8 akf = *(const bf16x8*)&shk[(st * 16 + lo) * LDK + hi * 8];
            const f32x4 en = __builtin_amdgcn_mfma_f32_16x16x32_bf16(
                akf, bq, (f32x4){0.f, 0.f, 0.f, 0.f}, 0, 0, 0);
            pw[st][0] = pk2bf(__expf(en[0]), __expf(en[1]));
            pw[st][1] = pk2bf(__expf(en[2]), __expf(en[3]));
        }
    }
    // F: att^T = V^T @ P^T; P B-frag from pw via bpermute
    f32x4 av[2];
    av[0] = av[1] = (f32x4){0.f, 0.f, 0.f, 0.f};
    {
        bf16x8 bp[2];
        #pragma unroll
        for (int kt = 0; kt < 2; ++kt) {
            unsigned wrd[4];
            #pragma unroll
            for (int uu = 0; uu < 4; ++uu) {
                const int adr = (uu < 2) ? addrA : addrB;
                const unsigned ev = __builtin_amdgcn_ds_bpermute(adr, (int)pw[2 * kt][uu & 1]);
                const unsigned od = __builtin_amdgcn_ds_bpermute(adr, (int)pw[2 * kt + 1][uu & 1]);
                wrd[uu] = (hi < 2) ? ev : od;
            }
            bp[kt] = __builtin_bit_cast(bf16x8, (uint4){wrd[0], wrd[1], wrd[2], wrd[3]});
        }
        #pragma unroll
        for (int nt = 0; nt < 2; ++nt)
            #pragma unroll
            for (int kt = 0; kt < 2; ++kt) {
                const bf16x8 avt = *(const bf16x8*)&shv[(nt * 16 + lo) * LDVT + kt * 32 + hi * 8];
                av[nt] = __builtin_amdgcn_mfma_f32_16x16x32_bf16(avt, bp[kt], av[nt], 0, 0, 0);
            }
    }
    // cosine vs in-register memories^T, store
    float d = 0.f, na = 0.f, nb = 0.f;
    #pragma unroll
    for (int nt = 0; nt < 2; ++nt)
        #pragma unroll
        for (int j = 0; j < 4; ++j) {
            const float av_ = av[nt][j], am_ = am[nt][j];
            d  = fmaf(av_, am_, d);
            na = fmaf(av_, av_, na);
            nb = fmaf(am_, am_, nb);
        }
    d  += __shfl_xor(d, 16);  d  += __shfl_xor(d, 32);
    na += __shfl_xor(na, 16); na += __shfl_xor(na, 32);
    nb += __shfl_xor(nb, 16); nb += __shfl_xor(nb, 32);
    if (hi == 0) {
        const float denom = fmaxf(sqrtf(na), 1e-8f) * fmaxf(sqrtf(nb), 1e-8f);
        out[((size_t)bn * Tc + w * 16 + lo) * Ec + e] = d / denom;
    }
}

__global__ __launch_bounds__(256, 4) void mg_mfma(
    const float* __restrict__ input,    // [B,N,T,2]
    const float* __restrict__ hidden,   // [E,B,N,T,C]
    const short* __restrict__ wt_img,   // [E][3][32][128] bf16, row-swizzled
    const short* __restrict__ bankM,    // [32][32] bf16 (memory^T, K zero-padded)
    const float* __restrict__ G2,       // [20][2] fp32
    float* __restrict__ out)            // [B,N,T,1,E]
{
    __shared__ __align__(16) short sh_wt[12288];      // 24576 B
    __shared__ __align__(16) short sh_k [Tc * LDK];   //  5120 B (single buffer)
    __shared__ __align__(16) short sh_vt[Mc * LDVT];  //  4608 B -> 34304 B, 4 blocks/CU

    const int t    = threadIdx.x;
    const int w    = t >> 6;
    const int lane = t & 63;
    const int lo   = lane & 15;
    const int hi   = lane >> 4;
    const int e    = blockIdx.x >> 11;
    const int bn0  = (blockIdx.x & 2047) * 2;
    const int bn1  = bn0 + 1;

    const int A01   = (((hi & 1) * 32) + lo) << 2;
    const int A23   = A01 + 64;
    const int addrA = (((hi & 1) * 2 + 0) * 16 + lo) * 4;
    const int addrB = (((hi & 1) * 2 + 1) * 16 + lo) * 4;

    // ---- A0: weight-slice DMA to LDS (6 x 4KB linear; image pre-swizzled)
    {
        const short* gsrc = wt_img + (size_t)e * 12288 + w * 512 + lane * 8;
        short* ldst = sh_wt + w * 512;
        #pragma unroll
        for (int c = 0; c < 6; ++c)
            gload_lds16(gsrc + c * 2048, ldst + c * 2048);
    }

    // ---- A1: unit-0 hidden loads + both units' input
    const float2 in2_0 = *(const float2*)(input + ((size_t)bn0 * Tc + lane) * 2);
    const float2 in2_1 = *(const float2*)(input + ((size_t)bn1 * Tc + lane) * 2);
    float4 h[8];
    {
        const float* hr0 = hidden + (((size_t)(e * 4096 + bn0)) * Tc + w * 16 + lo) * Cc + hi * 8;
        #pragma unroll
        for (int kt = 0; kt < 4; ++kt) {
            h[2 * kt]     = *(const float4*)(hr0 + kt * 32);
            h[2 * kt + 1] = *(const float4*)(hr0 + kt * 32 + 4);
        }
    }

    // ---- B0 + D0 in the load shadow
    f32x4 am0[2];
    {
        unsigned pd0[10];
        gate_pd(G2, in2_0, pd0);
        mem_read(bankM, pd0, lo, hi, w, am0);
    }

    // ---- convert unit-0 A-frags (drains h0)
    bf16x8 a0[4];
    #pragma unroll
    for (int kt = 0; kt < 4; ++kt) {
        const float4 x = h[2 * kt], y = h[2 * kt + 1];
        a0[kt] = __builtin_bit_cast(bf16x8, (uint4){pk2bf(x.x, x.y), pk2bf(x.z, x.w),
                                                    pk2bf(y.x, y.y), pk2bf(y.z, y.w)});
    }

    __syncthreads();   // #1: sh_wt visible (drains weight DMA)

    // ---- C(0): projections, write K0/V0 to LDS, pack Q0
    unsigned q_pk0[4];
    {
        f32x4 q_[2], k_[2], v_[2];
        proj(sh_wt, a0, lo, hi, q_, k_, v_);
        #pragma unroll
        for (int nt = 0; nt < 2; ++nt) {
            *(uint2*)&sh_k[(w * 16 + lo) * LDK + nt * 16 + hi * 4] =
                (uint2){pk2bf(k_[nt][0], k_[nt][1]), pk2bf(k_[nt][2], k_[nt][3])};
            #pragma unroll
            for (int j = 0; j < 4; ++j)
                sh_vt[(nt * 16 + hi * 4 + j) * LDVT + w * 16 + lo] = (short)f2bfu(v_[nt][j]);
            q_pk0[nt * 2]     = pk2bf(q_[nt][0], q_[nt][1]);
            q_pk0[nt * 2 + 1] = pk2bf(q_[nt][2], q_[nt][3]);
        }
    }

    __syncthreads();   // #2: K0/V0 ready

    // ---- issue unit-1 hidden loads NOW (fly under E+F(0) and B1/D1)
    {
        const float* hr1 = hidden + (((size_t)(e * 4096 + bn1)) * Tc + w * 16 + lo) * Cc + hi * 8;
        #pragma unroll
        for (int kt = 0; kt < 4; ++kt) {
            h[2 * kt]     = *(const float4*)(hr1 + kt * 32);
            h[2 * kt + 1] = *(const float4*)(hr1 + kt * 32 + 4);
        }
    }

    // ---- B1 + D1 (VALU/DS work in the unit-1 load shadow)
    f32x4 am1[2];
    {
        unsigned pd1[10];
        gate_pd(G2, in2_1, pd1);
        mem_read(bankM, pd1, lo, hi, w, am1);
    }

    // ---- E+F(0) + store
    attend_store(sh_k, sh_vt, q_pk0, am0, lo, hi, w, A01, A23, addrA, addrB, bn0, e, out);

    // ---- convert unit-1 A-frags (drains h1; by now latency is covered)
    bf16x8 a1[4];
    #pragma unroll
    for (int kt = 0; kt < 4; ++kt) {
        const float4 x = h[2 * kt], y = h[2 * kt + 1];
        a1[kt] = __builtin_bit_cast(bf16x8, (uint4){pk2bf(x.x, x.y), pk2bf(x.z, x.w),
                                                    pk2bf(y.x, y.y), pk2bf(y.z, y.w)});
    }

    __syncthreads();   // #3: WAR — all waves done reading K0/V0

    // ---- C(1): projections, write K1/V1 to the SAME buffers, pack Q1
    unsigned q_pk1[4];
    {
        f32x4 q_[2], k_[2], v_[2];
        proj(sh_wt, a1, lo, hi, q_, k_, v_);
        #pragma unroll
        for (int nt = 0; nt < 2; ++nt) {
            *(uint2*)&sh_k[(w * 16 + lo) * LDK + nt * 16 + hi * 4] =
                (uint2){pk2bf(k_[nt][0], k_[nt][1]), pk2bf(k_[nt][2], k_[nt][3])};
            #pragma unroll
            for (int j = 0; j < 4; ++j)
                sh_vt[(nt * 16 + hi * 4 + j) * LDVT + w * 16 + lo] = (short)f2bfu(v_[nt][j]);
            q_pk1[nt * 2]     = pk2bf(q_[nt][0], q_[nt][1]);
            q_pk1[nt * 2 + 1] = pk2bf(q_[nt][2], q_[nt][3]);
        }
    }

    __syncthreads();   // #4: K1/V1 ready

    // ---- E+F(1) + store
    attend_store(sh_k, sh_vt, q_pk1, am1, lo, hi, w, A01, A23, addrA, addrB, bn1, e, out);
}

extern "C" void kernel_launch(void* const* d_in, const int* in_sizes, int n_in,
                              void* d_out, int out_size, void* d_ws, size_t ws_size,
                              hipStream_t stream) {
    const float* input   = (const float*)d_in[0];
    const float* hidden  = (const float*)d_in[1];
    const float* membank = (const float*)d_in[2];
    const float* iq      = (const float*)d_in[3];
    const float* Wq      = (const float*)d_in[4];
    const float* Wk      = (const float*)d_in[5];
    const float* Wv      = (const float*)d_in[6];
    float* out = (float*)d_out;

    short* wt_img = (short*)d_ws;                      // 98304 B
    short* bankM  = (short*)((char*)d_ws + 98304);     //  2048 B
    float* G2     = (float*)((char*)d_ws + 100352);    //   160 B

    prep<<<193, 256, 0, stream>>>(Wq, Wk, Wv, membank, iq, wt_img, bankM, G2);
    mg_mfma<<<Ec * Bc * Nc / 2, 256, 0, stream>>>(input, hidden, wt_img, bankM, G2, out);
}